// Round 6
// baseline (499.373 us; speedup 1.0000x reference)
//
#include <hip/hip_runtime.h>

#define N_NODES 100000
#define N_EDGES 1600000
#define D 128
#define DH 256
#define N_GRAPHS 512
#define EPS 1e-5f
#define NPART 8
#define PSIZE 12500      // N_NODES / NPART
#define FCHUNK 4096      // edges per split chunk
#define PCAP 210000      // staging capacity per partition (~24 sigma)
#define SBSZ 196         // nodes per sub-bucket (64 per partition)
#define SBCAP 4608       // staging capacity per sub-bucket (~26 sigma)
#define CH2 8192         // edges per split2 block

typedef _Float16 h8 __attribute__((ext_vector_type(8)));
typedef float f4 __attribute__((ext_vector_type(4)));

// ---------------- preprocessing: fully-coalesced CSR build ----------------

__global__ __launch_bounds__(256) void k_split(const int* __restrict__ src,
                                               const int* __restrict__ dst,
                                               int* __restrict__ pcur,
                                               unsigned* __restrict__ staging) {
    int t = threadIdx.x;
    int base = blockIdx.x * FCHUNK;
    int dbuf[16], sbuf[16], pbuf[16];
#pragma unroll
    for (int j = 0; j < 16; ++j) {
        int i = base + j * 256 + t;
        bool v = i < N_EDGES;
        int d = v ? dst[i] : 0;
        dbuf[j] = d;
        sbuf[j] = v ? src[i] : 0;
        pbuf[j] = v ? d / PSIZE : 8;
    }
    int cnt_loc[8];
#pragma unroll
    for (int p = 0; p < 8; ++p) {
        int c = 0;
#pragma unroll
        for (int j = 0; j < 16; ++j) c += (pbuf[j] == p);
        cnt_loc[p] = c;
    }
    __shared__ int tmp[256][9];
#pragma unroll
    for (int p = 0; p < 8; ++p) tmp[t][p] = cnt_loc[p];
    __syncthreads();
    for (int off = 1; off < 256; off <<= 1) {
        int vals[8];
        if (t >= off) {
#pragma unroll
            for (int p = 0; p < 8; ++p) vals[p] = tmp[t - off][p];
        }
        __syncthreads();
        if (t >= off) {
#pragma unroll
            for (int p = 0; p < 8; ++p) tmp[t][p] += vals[p];
        }
        __syncthreads();
    }
    __shared__ int bbase_s[8];
    if (t < 8) bbase_s[t] = atomicAdd(&pcur[t], tmp[255][t]);
    __syncthreads();
#pragma unroll
    for (int p = 0; p < 8; ++p) {
        int off = bbase_s[p] + tmp[t][p] - cnt_loc[p];
        unsigned* sp = staging + (size_t)p * PCAP;
#pragma unroll
        for (int j = 0; j < 16; ++j) {
            if (pbuf[j] == p) {
                sp[off++] = ((unsigned)(dbuf[j] - p * PSIZE) << 17) | (unsigned)sbuf[j];
            }
        }
    }
}

__global__ __launch_bounds__(256) void k_split2(const unsigned* __restrict__ staging,
                                                const int* __restrict__ pcur,
                                                int* __restrict__ pcur2,
                                                unsigned* __restrict__ stag2) {
    int p = blockIdx.x & 7;
    int chunk = blockIdx.x >> 3;
    int total = min(pcur[p], PCAP);
    int base = chunk * CH2;
    if (base >= total) return;
    int lim = min(CH2, total - base);
    const unsigned* sp = staging + (size_t)p * PCAP + base;
    __shared__ unsigned buf[CH2];
    __shared__ int hist[64], scan[64], cur[64], gbase[64];
    int t = threadIdx.x;
    if (t < 64) hist[t] = 0;
    __syncthreads();
    for (int i = t; i < lim; i += 256) {
        unsigned pk = sp[i];
        atomicAdd(&hist[(pk >> 17) / SBSZ], 1);
    }
    __syncthreads();
    if (t < 64) {
        gbase[t] = atomicAdd(&pcur2[p * 64 + t], hist[t]);
        cur[t] = 0;
    }
    if (t == 0) {
        int acc = 0;
        for (int j = 0; j < 64; ++j) {
            scan[j] = acc;
            acc += hist[j];
        }
    }
    __syncthreads();
    for (int i = t; i < lim; i += 256) {
        unsigned pk = sp[i];
        int sb = (pk >> 17) / SBSZ;
        int r = atomicAdd(&cur[sb], 1);
        buf[scan[sb] + r] = pk;
    }
    __syncthreads();
    for (int sb = 0; sb < 64; ++sb) {
        int n = hist[sb];
        int gb = gbase[sb];
        if (gb >= SBCAP) continue;
        int nn = min(n, SBCAP - gb);
        unsigned* dstp = stag2 + ((size_t)(p * 64 + sb)) * SBCAP + gb;
        for (int i = t; i < nn; i += 256) dstp[i] = buf[scan[sb] + i];
    }
}

// counting sort by dst node + folded k_starts + folded global sub-bucket scan
// (each block redundantly scans pcur2[512] from L2; replaces k_sbscan dispatch)
__global__ __launch_bounds__(256) void k_sort3(const unsigned* __restrict__ stag2,
                                               const int* __restrict__ pcur2,
                                               const int* __restrict__ batch,
                                               int* __restrict__ offs,
                                               float* __restrict__ dinv,
                                               int* __restrict__ csr,
                                               int* __restrict__ starts) {
    int sb = blockIdx.x;  // 0..511
    int t = threadIdx.x;
    // ---- redundant inclusive scan of min(pcur2[i],SBCAP) over 512 entries ----
    __shared__ int gtmp[512];
    gtmp[t] = min(pcur2[t], SBCAP);
    gtmp[256 + t] = min(pcur2[256 + t], SBCAP);
    __syncthreads();
    for (int off = 1; off < 512; off <<= 1) {
        int a0 = (t >= off) ? gtmp[t - off] : 0;
        int a1 = gtmp[t + 256 - off];  // t+256-off >= 0 since off <= 256
        __syncthreads();
        if (t >= off) gtmp[t] += a0;
        gtmp[t + 256] += a1;
        __syncthreads();
    }
    int n = min(pcur2[sb], SBCAP);
    int gb = gtmp[sb] - n;
    if (sb == 511 && t == 0) offs[N_NODES] = gtmp[511];

    int p = sb >> 6, s = sb & 63;
    int node0 = p * PSIZE + s * SBSZ;
    int nloc = min(SBSZ, PSIZE - s * SBSZ);
    __shared__ int hist[256], scan[256], cur[SBSZ];
    __shared__ int sorted[SBCAP];
    for (int i = t; i < 256; i += 256) hist[i] = 0;
    for (int i = t; i < SBSZ; i += 256) cur[i] = 0;
    __syncthreads();
    const unsigned* sp = stag2 + (size_t)sb * SBCAP;
    for (int i = t; i < n; i += 256)
        atomicAdd(&hist[(int)(sp[i] >> 17) - s * SBSZ], 1);
    __syncthreads();
    // parallel inclusive scan of hist into scan (256 entries, Hillis-Steele)
    scan[t] = hist[t];
    __syncthreads();
    for (int off = 1; off < 256; off <<= 1) {
        int a = (t >= off) ? scan[t - off] : 0;
        __syncthreads();
        if (t >= off) scan[t] += a;
        __syncthreads();
    }
    // exclusive prefix for slot i is scan[i] - hist[i]
    for (int i = t; i < nloc; i += 256) {
        offs[node0 + i] = gb + scan[i] - hist[i];
        dinv[node0 + i] = rsqrtf((float)(hist[i] + 1));
    }
    for (int i = t; i < n; i += 256) {
        unsigned pk = sp[i];
        int dl = (int)(pk >> 17) - s * SBSZ;
        int r = atomicAdd(&cur[dl], 1);
        sorted[scan[dl] - hist[dl] + r] = (int)(pk & 0x1FFFFu);
    }
    __syncthreads();
    for (int i = t; i < n; i += 256) csr[gb + i] = sorted[i];
    // folded k_starts: handle this block's node range
    for (int i = t; i < nloc; i += 256) {
        int node = node0 + i;
        int b = batch[node];
        int prev = (node == 0) ? -1 : batch[node - 1];
        for (int g = prev + 1; g <= b; ++g) starts[g] = node;
        if (node == N_NODES - 1)
            for (int g = b + 1; g <= N_GRAPHS; ++g) starts[g] = N_NODES;
    }
}

// ------- MFMA GEMM with fused BN fold: Y'[n] = dinv[n]*(X[n]@(aW) + r) ------
template <bool F32IN, bool BN>
__global__ __launch_bounds__(256) void k_gemmf(const void* __restrict__ Xv,
                                               const float* __restrict__ W,
                                               const float* __restrict__ part,
                                               const float* __restrict__ g,
                                               const float* __restrict__ beta,
                                               const float* __restrict__ dinv,
                                               _Float16* __restrict__ Y, int nrows) {
    __shared__ _Float16 Wl[128][136];
    __shared__ _Float16 Yl[64][136];
    __shared__ float rs_[128];
    // as_/cs_ alias onto Yl (consumed before Yl's first write; 1 KB)
    float* asp = (float*)&Yl[0][0];
    float* csp = asp + 128;
    int t = threadIdx.x;
    if (BN) {
        if (t < 128) {
            float s = 0.f, s2 = 0.f;
            for (int st = 0; st < 32; ++st) {
                s += part[st * 256 + t];
                s2 += part[st * 256 + 128 + t];
            }
            float m = s * (1.0f / N_NODES);
            float v = s2 * (1.0f / N_NODES) - m * m;
            float ai = g[t] * rsqrtf(v + EPS);
            asp[t] = ai;
            csp[t] = beta[t] - m * ai;
        }
        __syncthreads();
    }
    // stage folded W into LDS: Wl[n][k] = fp16(as[k] * W[k][n]); coalesced reads
    for (int i = t; i < 128 * 128; i += 256) {
        int k = i >> 7, n = i & 127;
        float s = BN ? asp[k] : 1.0f;
        Wl[n][k] = (_Float16)(s * W[i]);
    }
    // r[n] = sum_k cs[k] * W[k][n]
    if (t < 128) {
        float s = 0.f;
        if (BN)
            for (int k = 0; k < D; ++k) s = fmaf(csp[k], W[k * D + t], s);
        rs_[t] = s;
    }

    int wave = t >> 6;
    int lane = t & 63;
    int l15 = lane & 15;
    int quad = lane >> 4;
    int rowblk = blockIdx.x * 64;
    int row0 = rowblk + wave * 16;

    h8 zero8;
#pragma unroll
    for (int j = 0; j < 8; ++j) zero8[j] = (_Float16)0;

    h8 a[4];
    bool inb = (row0 + l15) < nrows;
#pragma unroll
    for (int kt = 0; kt < 4; ++kt) a[kt] = zero8;
    if (inb) {
        if constexpr (F32IN) {
            const float* xrow = (const float*)Xv + (size_t)(row0 + l15) * D + quad * 8;
#pragma unroll
            for (int kt = 0; kt < 4; ++kt) {
                float4 u = *(const float4*)(xrow + kt * 32);
                float4 w = *(const float4*)(xrow + kt * 32 + 4);
                h8 o;
                o[0] = (_Float16)u.x; o[1] = (_Float16)u.y;
                o[2] = (_Float16)u.z; o[3] = (_Float16)u.w;
                o[4] = (_Float16)w.x; o[5] = (_Float16)w.y;
                o[6] = (_Float16)w.z; o[7] = (_Float16)w.w;
                a[kt] = o;
            }
        } else {
            const _Float16* xrow = (const _Float16*)Xv + (size_t)(row0 + l15) * D + quad * 8;
#pragma unroll
            for (int kt = 0; kt < 4; ++kt) a[kt] = *(const h8*)(xrow + kt * 32);
        }
    }

    __syncthreads();

    f4 acc[8];
#pragma unroll
    for (int n = 0; n < 8; ++n) {
        acc[n][0] = 0.f; acc[n][1] = 0.f; acc[n][2] = 0.f; acc[n][3] = 0.f;
#pragma unroll
        for (int kt = 0; kt < 4; ++kt) {
            h8 b = *(const h8*)&Wl[n * 16 + l15][kt * 32 + quad * 8];
            acc[n] = __builtin_amdgcn_mfma_f32_16x16x32_f16(a[kt], b, acc[n], 0, 0, 0);
        }
    }
    float dv[4];
    int rbase = rowblk + wave * 16 + quad * 4;
#pragma unroll
    for (int i = 0; i < 4; ++i)
        dv[i] = (rbase + i < nrows) ? dinv[rbase + i] : 0.f;
#pragma unroll
    for (int n = 0; n < 8; ++n) {
        float r = rs_[n * 16 + l15];
#pragma unroll
        for (int i = 0; i < 4; ++i)
            Yl[wave * 16 + quad * 4 + i][n * 16 + l15] = (_Float16)((acc[n][i] + r) * dv[i]);
    }
    __syncthreads();
    for (int i = t; i < 64 * 16; i += 256) {
        int r = i >> 4, c = i & 15;
        if (rowblk + r < nrows)
            *(h8*)&Y[(size_t)(rowblk + r) * D + c * 8] = *(h8*)&Yl[r][c * 8];
    }
}

// ------ aggregate + relu + fused BN partial stats (nt csr stream) ------
__global__ __launch_bounds__(256) void k_aggregate(const h8* __restrict__ Y8,
                                                   const int* __restrict__ offs,
                                                   const int* __restrict__ csr,
                                                   const float* __restrict__ dinv,
                                                   const float* __restrict__ bias,
                                                   h8* __restrict__ A8,
                                                   float* __restrict__ part) {
    int grp = threadIdx.x >> 4;
    int lane = threadIdx.x & 15;
    int node = blockIdx.x * 16 + grp;
    int beg = offs[node], end = offs[node + 1];
    float dn = dinv[node];
    float acc[8];
    h8 y = Y8[(size_t)node * 16 + lane];
#pragma unroll
    for (int i = 0; i < 8; ++i) acc[i] = (float)y[i];
    int e = beg;
    for (; e + 7 < end; e += 8) {
        int s0 = __builtin_nontemporal_load(csr + e);
        int s1 = __builtin_nontemporal_load(csr + e + 1);
        int s2 = __builtin_nontemporal_load(csr + e + 2);
        int s3 = __builtin_nontemporal_load(csr + e + 3);
        int s4 = __builtin_nontemporal_load(csr + e + 4);
        int s5 = __builtin_nontemporal_load(csr + e + 5);
        int s6 = __builtin_nontemporal_load(csr + e + 6);
        int s7 = __builtin_nontemporal_load(csr + e + 7);
        h8 v0 = Y8[(size_t)s0 * 16 + lane];
        h8 v1 = Y8[(size_t)s1 * 16 + lane];
        h8 v2 = Y8[(size_t)s2 * 16 + lane];
        h8 v3 = Y8[(size_t)s3 * 16 + lane];
        h8 v4 = Y8[(size_t)s4 * 16 + lane];
        h8 v5 = Y8[(size_t)s5 * 16 + lane];
        h8 v6 = Y8[(size_t)s6 * 16 + lane];
        h8 v7 = Y8[(size_t)s7 * 16 + lane];
#pragma unroll
        for (int i = 0; i < 8; ++i) {
            acc[i] += (float)v0[i] + (float)v1[i] + (float)v2[i] + (float)v3[i];
            acc[i] += (float)v4[i] + (float)v5[i] + (float)v6[i] + (float)v7[i];
        }
    }
    if (e + 3 < end) {
        int s0 = __builtin_nontemporal_load(csr + e);
        int s1 = __builtin_nontemporal_load(csr + e + 1);
        int s2 = __builtin_nontemporal_load(csr + e + 2);
        int s3 = __builtin_nontemporal_load(csr + e + 3);
        h8 v0 = Y8[(size_t)s0 * 16 + lane];
        h8 v1 = Y8[(size_t)s1 * 16 + lane];
        h8 v2 = Y8[(size_t)s2 * 16 + lane];
        h8 v3 = Y8[(size_t)s3 * 16 + lane];
#pragma unroll
        for (int i = 0; i < 8; ++i)
            acc[i] += (float)v0[i] + (float)v1[i] + (float)v2[i] + (float)v3[i];
        e += 4;
    }
    for (; e < end; ++e) {
        int s = __builtin_nontemporal_load(csr + e);
        h8 v = Y8[(size_t)s * 16 + lane];
#pragma unroll
        for (int i = 0; i < 8; ++i) acc[i] += (float)v[i];
    }
    __shared__ float red[16][128];
    h8 o;
#pragma unroll
    for (int i = 0; i < 8; ++i) {
        float v = fmaxf(fmaf(acc[i], dn, bias[lane * 8 + i]), 0.f);
        o[i] = (_Float16)v;
        red[grp][lane * 8 + i] = v;
    }
    __builtin_nontemporal_store(o, &A8[(size_t)node * 16 + lane]);
    __syncthreads();
    if (threadIdx.x < 128) {
        int c = threadIdx.x;
        float s = 0.f, s2 = 0.f;
#pragma unroll
        for (int g = 0; g < 16; ++g) {
            float v = red[g][c];
            s += v;
            s2 = fmaf(v, v, s2);
        }
        float* p = part + (size_t)(blockIdx.x & 31) * 256;
        atomicAdd(&p[c], s);
        atomicAdd(&p[128 + c], s2);
    }
}

// ---------------- pooling (+ fused layer-3 BN coeffs) ----------------
__global__ __launch_bounds__(256) void k_pool(const h8* __restrict__ x8,
                                              const int* __restrict__ starts,
                                              const float* __restrict__ part,
                                              const float* __restrict__ g,
                                              const float* __restrict__ beta,
                                              float* __restrict__ pooled) {
    __shared__ float a_s[128], c_s[128];
    int t = threadIdx.x;
    if (t < 128) {
        float s = 0.f, s2 = 0.f;
        for (int st = 0; st < 32; ++st) {
            s += part[st * 256 + t];
            s2 += part[st * 256 + 128 + t];
        }
        float m = s * (1.0f / N_NODES);
        float v = s2 * (1.0f / N_NODES) - m * m;
        float ai = g[t] * rsqrtf(v + EPS);
        a_s[t] = ai;
        c_s[t] = beta[t] - m * ai;
    }
    __syncthreads();
    int gg = blockIdx.x;
    int grp = t >> 4;
    int lane = t & 15;
    int beg = starts[gg], end = starts[gg + 1];
    float s[8] = {};
    for (int n = beg + grp; n < end; n += 16) {
        h8 v = x8[(size_t)n * 16 + lane];
#pragma unroll
        for (int i = 0; i < 8; ++i) s[i] += (float)v[i];
    }
    __shared__ float red[16][128];
#pragma unroll
    for (int i = 0; i < 8; ++i) red[grp][lane * 8 + i] = s[i];
    __syncthreads();
    if (t < 128) {
        int ch = t;
        float tt = 0.f;
#pragma unroll
        for (int gi = 0; gi < 16; ++gi) tt += red[gi][ch];
        float cnt = (float)(end - beg);
        pooled[gg * D + ch] = fmaf(a_s[ch], tt, cnt * c_s[ch]);
    }
}

// dense + relu + fused stats atomics; BN coeffs computed in-block from stats_in
template <int K, bool BN>
__global__ __launch_bounds__(256) void k_dense(const float* __restrict__ in,
                                               const float* __restrict__ W,
                                               const float* __restrict__ b,
                                               const float* __restrict__ stats_in,
                                               const float* __restrict__ g,
                                               const float* __restrict__ beta,
                                               float* __restrict__ out,
                                               float* __restrict__ stats_out) {
    __shared__ float inl[K];
    __shared__ float a_s[K > 128 ? K : 1], c_s[K > 128 ? K : 1];
    int t = threadIdx.x;
    if (BN) {
        float s = 0.f, s2 = 0.f;
        for (int st = 0; st < 8; ++st) {
            s += stats_in[st * 512 + t];
            s2 += stats_in[st * 512 + 256 + t];
        }
        float m = s * (1.0f / N_GRAPHS);
        float v = s2 * (1.0f / N_GRAPHS) - m * m;
        float ai = g[t] * rsqrtf(v + EPS);
        a_s[t] = ai;
        c_s[t] = beta[t] - m * ai;
        __syncthreads();
    }
    int row = blockIdx.x;
    for (int k = t; k < K; k += 256) {
        float v = in[row * K + k];
        if (BN) v = fmaf(v, a_s[k], c_s[k]);
        inl[k] = v;
    }
    __syncthreads();
    int j = t;
    float acc = b[j];
#pragma unroll
    for (int k = 0; k < K; ++k) acc = fmaf(inl[k], W[k * 256 + j], acc);
    float v = fmaxf(acc, 0.0f);
    out[row * 256 + j] = v;
    float* sp = stats_out + (size_t)(row & 7) * 512;
    atomicAdd(&sp[j], v);
    atomicAdd(&sp[256 + j], v * v);
}

// final dot with h1's BN computed in-block and applied in-register
__global__ __launch_bounds__(256) void k_final(const float* __restrict__ h,
                                               const float* __restrict__ stats_in,
                                               const float* __restrict__ gg,
                                               const float* __restrict__ beta,
                                               const float* __restrict__ Wout,
                                               const float* __restrict__ bout,
                                               float* __restrict__ out) {
    __shared__ float a_s[256], c_s[256];
    int t = threadIdx.x;
    {
        float s = 0.f, s2 = 0.f;
        for (int st = 0; st < 8; ++st) {
            s += stats_in[st * 512 + t];
            s2 += stats_in[st * 512 + 256 + t];
        }
        float m = s * (1.0f / N_GRAPHS);
        float v = s2 * (1.0f / N_GRAPHS) - m * m;
        float ai = gg[t] * rsqrtf(v + EPS);
        a_s[t] = ai;
        c_s[t] = beta[t] - m * ai;
    }
    __syncthreads();
    int g = blockIdx.x * 4 + (t >> 6);
    int lane = t & 63;
    float4 v = ((const float4*)(h + g * DH))[lane];
    float4 av = ((const float4*)a_s)[lane];
    float4 cv = ((const float4*)c_s)[lane];
    float4 w = ((const float4*)Wout)[lane];
    v.x = fmaf(v.x, av.x, cv.x);
    v.y = fmaf(v.y, av.y, cv.y);
    v.z = fmaf(v.z, av.z, cv.z);
    v.w = fmaf(v.w, av.w, cv.w);
    float acc = v.x * w.x + v.y * w.y + v.z * w.z + v.w * w.w;
#pragma unroll
    for (int off = 32; off; off >>= 1) acc += __shfl_down(acc, off, 64);
    if (lane == 0) out[g] = acc + bout[0];
}

// ---------------- launch ----------------

extern "C" void kernel_launch(void* const* d_in, const int* in_sizes, int n_in,
                              void* d_out, int out_size, void* d_ws, size_t ws_size,
                              hipStream_t stream) {
    const float* x = (const float*)d_in[0];
    const int* ei = (const int*)d_in[1];
    const int* batch = (const int*)d_in[2];
    const float* Wc = (const float*)d_in[3];
    const float* bc = (const float*)d_in[4];
    const float* gc = (const float*)d_in[5];
    const float* bec = (const float*)d_in[6];
    const float* Wh0 = (const float*)d_in[7];
    const float* bh0 = (const float*)d_in[8];
    const float* gh0 = (const float*)d_in[9];
    const float* beh0 = (const float*)d_in[10];
    const float* Wh1 = (const float*)d_in[11];
    const float* bh1 = (const float*)d_in[12];
    const float* gh1 = (const float*)d_in[13];
    const float* beh1 = (const float*)d_in[14];
    const float* Wout = (const float*)d_in[15];
    const float* bout = (const float*)d_in[16];
    float* out = (float*)d_out;

    const int* src = ei;
    const int* dst = ei + N_EDGES;

    char* base = (char*)d_ws;
    size_t woff = 0;
    auto alloc = [&](size_t bytes) -> char* {
        char* p = base + woff;
        woff = (woff + bytes + 255) & ~(size_t)255;
        return p;
    };
    _Float16* bufY = (_Float16*)alloc(sizeof(_Float16) * (size_t)N_NODES * D);
    _Float16* bufA = (_Float16*)alloc(sizeof(_Float16) * (size_t)N_NODES * D);
    float* dinv = (float*)alloc(sizeof(float) * N_NODES);
    int* csr = (int*)alloc(sizeof(int) * N_EDGES);
    unsigned* staging = (unsigned*)alloc(sizeof(unsigned) * 8 * PCAP);
    unsigned* stag2 = (unsigned*)alloc(sizeof(unsigned) * 512 * SBCAP);
    // zeroed: pcur(64) + pcur2(512) + part[3](3*32*256) + stats[2](2*8*512)
    size_t zero_bytes = sizeof(int) * (64 + 512) + sizeof(float) * (3 * 32 * 256 + 2 * 8 * 512);
    char* zero_base = alloc(zero_bytes);
    int* pcur = (int*)zero_base;
    int* pcur2 = pcur + 64;
    float* part = (float*)(pcur2 + 512);   // 3 layer-indexed buffers
    float* stats0 = part + 3 * 32 * 256;   // h0: 8 stripes x (256 sums + 256 sq)
    float* stats1 = stats0 + 8 * 512;      // h1
    int* offs = (int*)alloc(sizeof(int) * (N_NODES + 1));
    int* starts = (int*)alloc(sizeof(int) * (N_GRAPHS + 1));
    float* pooled = (float*)alloc(sizeof(float) * N_GRAPHS * D);
    float* h0 = (float*)alloc(sizeof(float) * N_GRAPHS * DH);
    float* h1 = (float*)alloc(sizeof(float) * N_GRAPHS * DH);

    hipMemsetAsync(zero_base, 0, zero_bytes, stream);

    int split_grid = (N_EDGES + FCHUNK - 1) / FCHUNK;
    int split2_grid = ((PCAP + CH2 - 1) / CH2) * 8;
    k_split<<<split_grid, 256, 0, stream>>>(src, dst, pcur, staging);
    k_split2<<<split2_grid, 256, 0, stream>>>(staging, pcur, pcur2, stag2);
    k_sort3<<<512, 256, 0, stream>>>(stag2, pcur2, batch, offs, dinv, csr, starts);

    int gemm_grid = (N_NODES + 63) / 64;
    int agg_grid = N_NODES / 16;
    // layer 0: no BN fold (W used as-is), input fp32 x
    k_gemmf<true, false><<<gemm_grid, 256, 0, stream>>>(
        x, Wc + 0 * D * D, nullptr, nullptr, nullptr, dinv, bufY, N_NODES);
    k_aggregate<<<agg_grid, 256, 0, stream>>>((const h8*)bufY, offs, csr, dinv,
                                              bc + 0 * D, (h8*)bufA, part);
    // layer 1: BN fold from part0
    k_gemmf<false, true><<<gemm_grid, 256, 0, stream>>>(
        bufA, Wc + 1 * D * D, part, gc + 0 * D, bec + 0 * D, dinv, bufY, N_NODES);
    k_aggregate<<<agg_grid, 256, 0, stream>>>((const h8*)bufY, offs, csr, dinv,
                                              bc + 1 * D, (h8*)bufA,
                                              part + 1 * 32 * 256);
    // layer 2: BN fold from part1
    k_gemmf<false, true><<<gemm_grid, 256, 0, stream>>>(
        bufA, Wc + 2 * D * D, part + 1 * 32 * 256, gc + 1 * D, bec + 1 * D, dinv,
        bufY, N_NODES);
    k_aggregate<<<agg_grid, 256, 0, stream>>>((const h8*)bufY, offs, csr, dinv,
                                              bc + 2 * D, (h8*)bufA,
                                              part + 2 * 32 * 256);

    // pool with fused layer-3 BN coeffs
    k_pool<<<N_GRAPHS, 256, 0, stream>>>((const h8*)bufA, starts,
                                         part + 2 * 32 * 256, gc + 2 * D,
                                         bec + 2 * D, pooled);

    k_dense<128, false><<<N_GRAPHS, 256, 0, stream>>>(pooled, Wh0, bh0, nullptr,
                                                      nullptr, nullptr, h0, stats0);
    k_dense<256, true><<<N_GRAPHS, 256, 0, stream>>>(h0, Wh1, bh1, stats0, gh0,
                                                     beh0, h1, stats1);
    k_final<<<N_GRAPHS / 4, 256, 0, stream>>>(h1, stats1, gh1, beh1, Wout, bout,
                                              out);
}

// Round 7
// 480.804 us; speedup vs baseline: 1.0386x; 1.0386x over previous
//
#include <hip/hip_runtime.h>

#define N_NODES 100000
#define N_EDGES 1600000
#define D 128
#define DH 256
#define N_GRAPHS 512
#define EPS 1e-5f
#define NPART 8
#define PSIZE 12500      // N_NODES / NPART
#define FCHUNK 4096      // edges per split chunk
#define PCAP 210000      // staging capacity per partition (~24 sigma)
#define SBSZ 196         // nodes per sub-bucket (64 per partition)
#define SBCAP 4608       // staging capacity per sub-bucket (~26 sigma)
#define CH2 8192         // edges per split2 block

typedef _Float16 h8 __attribute__((ext_vector_type(8)));
typedef float f4 __attribute__((ext_vector_type(4)));

// ---------------- preprocessing: fully-coalesced CSR build ----------------

__global__ __launch_bounds__(256) void k_split(const int* __restrict__ src,
                                               const int* __restrict__ dst,
                                               int* __restrict__ pcur,
                                               unsigned* __restrict__ staging) {
    int t = threadIdx.x;
    int base = blockIdx.x * FCHUNK;
    int dbuf[16], sbuf[16], pbuf[16];
#pragma unroll
    for (int j = 0; j < 16; ++j) {
        int i = base + j * 256 + t;
        bool v = i < N_EDGES;
        int d = v ? dst[i] : 0;
        dbuf[j] = d;
        sbuf[j] = v ? src[i] : 0;
        pbuf[j] = v ? d / PSIZE : 8;
    }
    int cnt_loc[8];
#pragma unroll
    for (int p = 0; p < 8; ++p) {
        int c = 0;
#pragma unroll
        for (int j = 0; j < 16; ++j) c += (pbuf[j] == p);
        cnt_loc[p] = c;
    }
    __shared__ int tmp[256][9];
#pragma unroll
    for (int p = 0; p < 8; ++p) tmp[t][p] = cnt_loc[p];
    __syncthreads();
    for (int off = 1; off < 256; off <<= 1) {
        int vals[8];
        if (t >= off) {
#pragma unroll
            for (int p = 0; p < 8; ++p) vals[p] = tmp[t - off][p];
        }
        __syncthreads();
        if (t >= off) {
#pragma unroll
            for (int p = 0; p < 8; ++p) tmp[t][p] += vals[p];
        }
        __syncthreads();
    }
    __shared__ int bbase_s[8];
    if (t < 8) bbase_s[t] = atomicAdd(&pcur[t], tmp[255][t]);
    __syncthreads();
#pragma unroll
    for (int p = 0; p < 8; ++p) {
        int off = bbase_s[p] + tmp[t][p] - cnt_loc[p];
        unsigned* sp = staging + (size_t)p * PCAP;
#pragma unroll
        for (int j = 0; j < 16; ++j) {
            if (pbuf[j] == p) {
                sp[off++] = ((unsigned)(dbuf[j] - p * PSIZE) << 17) | (unsigned)sbuf[j];
            }
        }
    }
}

__global__ __launch_bounds__(256) void k_split2(const unsigned* __restrict__ staging,
                                                const int* __restrict__ pcur,
                                                int* __restrict__ pcur2,
                                                unsigned* __restrict__ stag2) {
    int p = blockIdx.x & 7;
    int chunk = blockIdx.x >> 3;
    int total = min(pcur[p], PCAP);
    int base = chunk * CH2;
    if (base >= total) return;
    int lim = min(CH2, total - base);
    const unsigned* sp = staging + (size_t)p * PCAP + base;
    __shared__ unsigned buf[CH2];
    __shared__ int hist[64], scan[64], cur[64], gbase[64];
    int t = threadIdx.x;
    if (t < 64) hist[t] = 0;
    __syncthreads();
    for (int i = t; i < lim; i += 256) {
        unsigned pk = sp[i];
        atomicAdd(&hist[(pk >> 17) / SBSZ], 1);
    }
    __syncthreads();
    if (t < 64) {
        gbase[t] = atomicAdd(&pcur2[p * 64 + t], hist[t]);
        cur[t] = 0;
    }
    if (t == 0) {
        int acc = 0;
        for (int j = 0; j < 64; ++j) {
            scan[j] = acc;
            acc += hist[j];
        }
    }
    __syncthreads();
    for (int i = t; i < lim; i += 256) {
        unsigned pk = sp[i];
        int sb = (pk >> 17) / SBSZ;
        int r = atomicAdd(&cur[sb], 1);
        buf[scan[sb] + r] = pk;
    }
    __syncthreads();
    for (int sb = 0; sb < 64; ++sb) {
        int n = hist[sb];
        int gb = gbase[sb];
        if (gb >= SBCAP) continue;
        int nn = min(n, SBCAP - gb);
        unsigned* dstp = stag2 + ((size_t)(p * 64 + sb)) * SBCAP + gb;
        for (int i = t; i < nn; i += 256) dstp[i] = buf[scan[sb] + i];
    }
}

// counting sort by dst node + folded k_starts + folded global sub-bucket scan
// + degree-sorted node permutation (equalizes degree within aggregate waves)
__global__ __launch_bounds__(256) void k_sort3(const unsigned* __restrict__ stag2,
                                               const int* __restrict__ pcur2,
                                               const int* __restrict__ batch,
                                               int* __restrict__ offs,
                                               float* __restrict__ dinv,
                                               int* __restrict__ csr,
                                               int* __restrict__ starts,
                                               int* __restrict__ perm) {
    int sb = blockIdx.x;  // 0..511
    int t = threadIdx.x;
    // ---- redundant inclusive scan of min(pcur2[i],SBCAP) over 512 entries ----
    __shared__ int gtmp[512];
    gtmp[t] = min(pcur2[t], SBCAP);
    gtmp[256 + t] = min(pcur2[256 + t], SBCAP);
    __syncthreads();
    for (int off = 1; off < 512; off <<= 1) {
        int a0 = (t >= off) ? gtmp[t - off] : 0;
        int a1 = gtmp[t + 256 - off];  // t+256-off >= 0 since off <= 256
        __syncthreads();
        if (t >= off) gtmp[t] += a0;
        gtmp[t + 256] += a1;
        __syncthreads();
    }
    int n = min(pcur2[sb], SBCAP);
    int gb = gtmp[sb] - n;
    if (sb == 511 && t == 0) offs[N_NODES] = gtmp[511];

    int p = sb >> 6, s = sb & 63;
    int node0 = p * PSIZE + s * SBSZ;
    int nloc = min(SBSZ, PSIZE - s * SBSZ);
    __shared__ int hist[256], scan[256], cur[SBSZ];
    __shared__ int sorted[SBCAP];
    __shared__ int dh[64], dscan[64], dcur[64];
    for (int i = t; i < 256; i += 256) hist[i] = 0;
    for (int i = t; i < SBSZ; i += 256) cur[i] = 0;
    if (t < 64) {
        dh[t] = 0;
        dcur[t] = 0;
    }
    __syncthreads();
    const unsigned* sp = stag2 + (size_t)sb * SBCAP;
    for (int i = t; i < n; i += 256)
        atomicAdd(&hist[(int)(sp[i] >> 17) - s * SBSZ], 1);
    __syncthreads();
    // parallel inclusive scan of hist into scan (256 entries, Hillis-Steele)
    scan[t] = hist[t];
    __syncthreads();
    for (int off = 1; off < 256; off <<= 1) {
        int a = (t >= off) ? scan[t - off] : 0;
        __syncthreads();
        if (t >= off) scan[t] += a;
        __syncthreads();
    }
    // exclusive prefix for slot i is scan[i] - hist[i]
    for (int i = t; i < nloc; i += 256) {
        offs[node0 + i] = gb + scan[i] - hist[i];
        dinv[node0 + i] = rsqrtf((float)(hist[i] + 1));
        atomicAdd(&dh[min(hist[i], 63)], 1);
    }
    for (int i = t; i < n; i += 256) {
        unsigned pk = sp[i];
        int dl = (int)(pk >> 17) - s * SBSZ;
        int r = atomicAdd(&cur[dl], 1);
        sorted[scan[dl] - hist[dl] + r] = (int)(pk & 0x1FFFFu);
    }
    __syncthreads();
    for (int i = t; i < n; i += 256) csr[gb + i] = sorted[i];
    // degree-bin exclusive scan + scatter permutation (rank by degree)
    if (t == 0) {
        int acc = 0;
        for (int j = 0; j < 64; ++j) {
            dscan[j] = acc;
            acc += dh[j];
        }
    }
    __syncthreads();
    for (int i = t; i < nloc; i += 256) {
        int d = min(hist[i], 63);
        int r = atomicAdd(&dcur[d], 1);
        perm[node0 + dscan[d] + r] = node0 + i;
    }
    // folded k_starts: handle this block's node range
    for (int i = t; i < nloc; i += 256) {
        int node = node0 + i;
        int b = batch[node];
        int prev = (node == 0) ? -1 : batch[node - 1];
        for (int g = prev + 1; g <= b; ++g) starts[g] = node;
        if (node == N_NODES - 1)
            for (int g = b + 1; g <= N_GRAPHS; ++g) starts[g] = N_NODES;
    }
}

// ------- MFMA GEMM with fused BN fold: Y'[n] = dinv[n]*(X[n]@(aW) + r) ------
template <bool F32IN, bool BN>
__global__ __launch_bounds__(256) void k_gemmf(const void* __restrict__ Xv,
                                               const float* __restrict__ W,
                                               const float* __restrict__ part,
                                               const float* __restrict__ g,
                                               const float* __restrict__ beta,
                                               const float* __restrict__ dinv,
                                               _Float16* __restrict__ Y, int nrows) {
    __shared__ _Float16 Wl[128][136];
    __shared__ _Float16 Yl[64][136];
    __shared__ float rs_[128];
    // as_/cs_ alias onto Yl (consumed before Yl's first write; 1 KB)
    float* asp = (float*)&Yl[0][0];
    float* csp = asp + 128;
    int t = threadIdx.x;
    if (BN) {
        if (t < 128) {
            float s = 0.f, s2 = 0.f;
            for (int st = 0; st < 32; ++st) {
                s += part[st * 256 + t];
                s2 += part[st * 256 + 128 + t];
            }
            float m = s * (1.0f / N_NODES);
            float v = s2 * (1.0f / N_NODES) - m * m;
            float ai = g[t] * rsqrtf(v + EPS);
            asp[t] = ai;
            csp[t] = beta[t] - m * ai;
        }
        __syncthreads();
    }
    // stage folded W into LDS: Wl[n][k] = fp16(as[k] * W[k][n]); coalesced reads
    for (int i = t; i < 128 * 128; i += 256) {
        int k = i >> 7, n = i & 127;
        float s = BN ? asp[k] : 1.0f;
        Wl[n][k] = (_Float16)(s * W[i]);
    }
    // r[n] = sum_k cs[k] * W[k][n]
    if (t < 128) {
        float s = 0.f;
        if (BN)
            for (int k = 0; k < D; ++k) s = fmaf(csp[k], W[k * D + t], s);
        rs_[t] = s;
    }

    int wave = t >> 6;
    int lane = t & 63;
    int l15 = lane & 15;
    int quad = lane >> 4;
    int rowblk = blockIdx.x * 64;
    int row0 = rowblk + wave * 16;

    h8 zero8;
#pragma unroll
    for (int j = 0; j < 8; ++j) zero8[j] = (_Float16)0;

    h8 a[4];
    bool inb = (row0 + l15) < nrows;
#pragma unroll
    for (int kt = 0; kt < 4; ++kt) a[kt] = zero8;
    if (inb) {
        if constexpr (F32IN) {
            const float* xrow = (const float*)Xv + (size_t)(row0 + l15) * D + quad * 8;
#pragma unroll
            for (int kt = 0; kt < 4; ++kt) {
                float4 u = *(const float4*)(xrow + kt * 32);
                float4 w = *(const float4*)(xrow + kt * 32 + 4);
                h8 o;
                o[0] = (_Float16)u.x; o[1] = (_Float16)u.y;
                o[2] = (_Float16)u.z; o[3] = (_Float16)u.w;
                o[4] = (_Float16)w.x; o[5] = (_Float16)w.y;
                o[6] = (_Float16)w.z; o[7] = (_Float16)w.w;
                a[kt] = o;
            }
        } else {
            const _Float16* xrow = (const _Float16*)Xv + (size_t)(row0 + l15) * D + quad * 8;
#pragma unroll
            for (int kt = 0; kt < 4; ++kt) a[kt] = *(const h8*)(xrow + kt * 32);
        }
    }

    __syncthreads();

    f4 acc[8];
#pragma unroll
    for (int n = 0; n < 8; ++n) {
        acc[n][0] = 0.f; acc[n][1] = 0.f; acc[n][2] = 0.f; acc[n][3] = 0.f;
#pragma unroll
        for (int kt = 0; kt < 4; ++kt) {
            h8 b = *(const h8*)&Wl[n * 16 + l15][kt * 32 + quad * 8];
            acc[n] = __builtin_amdgcn_mfma_f32_16x16x32_f16(a[kt], b, acc[n], 0, 0, 0);
        }
    }
    float dv[4];
    int rbase = rowblk + wave * 16 + quad * 4;
#pragma unroll
    for (int i = 0; i < 4; ++i)
        dv[i] = (rbase + i < nrows) ? dinv[rbase + i] : 0.f;
#pragma unroll
    for (int n = 0; n < 8; ++n) {
        float r = rs_[n * 16 + l15];
#pragma unroll
        for (int i = 0; i < 4; ++i)
            Yl[wave * 16 + quad * 4 + i][n * 16 + l15] = (_Float16)((acc[n][i] + r) * dv[i]);
    }
    __syncthreads();
    for (int i = t; i < 64 * 16; i += 256) {
        int r = i >> 4, c = i & 15;
        if (rowblk + r < nrows)
            *(h8*)&Y[(size_t)(rowblk + r) * D + c * 8] = *(h8*)&Yl[r][c * 8];
    }
}

// ------ aggregate + relu + fused BN partial stats (degree-uniform waves) ------
__global__ __launch_bounds__(256) void k_aggregate(const h8* __restrict__ Y8,
                                                   const int* __restrict__ offs,
                                                   const int* __restrict__ csr,
                                                   const float* __restrict__ dinv,
                                                   const float* __restrict__ bias,
                                                   const int* __restrict__ perm,
                                                   h8* __restrict__ A8,
                                                   float* __restrict__ part) {
    int grp = threadIdx.x >> 4;
    int lane = threadIdx.x & 15;
    int node = perm[blockIdx.x * 16 + grp];
    int beg = offs[node], end = offs[node + 1];
    float dn = dinv[node];
    float acc[8];
    h8 y = Y8[(size_t)node * 16 + lane];
#pragma unroll
    for (int i = 0; i < 8; ++i) acc[i] = (float)y[i];
    int e = beg;
    for (; e + 7 < end; e += 8) {
        int s0 = csr[e], s1 = csr[e + 1], s2 = csr[e + 2], s3 = csr[e + 3];
        int s4 = csr[e + 4], s5 = csr[e + 5], s6 = csr[e + 6], s7 = csr[e + 7];
        h8 v0 = Y8[(size_t)s0 * 16 + lane];
        h8 v1 = Y8[(size_t)s1 * 16 + lane];
        h8 v2 = Y8[(size_t)s2 * 16 + lane];
        h8 v3 = Y8[(size_t)s3 * 16 + lane];
        h8 v4 = Y8[(size_t)s4 * 16 + lane];
        h8 v5 = Y8[(size_t)s5 * 16 + lane];
        h8 v6 = Y8[(size_t)s6 * 16 + lane];
        h8 v7 = Y8[(size_t)s7 * 16 + lane];
#pragma unroll
        for (int i = 0; i < 8; ++i) {
            acc[i] += (float)v0[i] + (float)v1[i] + (float)v2[i] + (float)v3[i];
            acc[i] += (float)v4[i] + (float)v5[i] + (float)v6[i] + (float)v7[i];
        }
    }
    if (e + 3 < end) {
        int s0 = csr[e], s1 = csr[e + 1], s2 = csr[e + 2], s3 = csr[e + 3];
        h8 v0 = Y8[(size_t)s0 * 16 + lane];
        h8 v1 = Y8[(size_t)s1 * 16 + lane];
        h8 v2 = Y8[(size_t)s2 * 16 + lane];
        h8 v3 = Y8[(size_t)s3 * 16 + lane];
#pragma unroll
        for (int i = 0; i < 8; ++i)
            acc[i] += (float)v0[i] + (float)v1[i] + (float)v2[i] + (float)v3[i];
        e += 4;
    }
    for (; e < end; ++e) {
        int s = csr[e];
        h8 v = Y8[(size_t)s * 16 + lane];
#pragma unroll
        for (int i = 0; i < 8; ++i) acc[i] += (float)v[i];
    }
    __shared__ float red[16][128];
    h8 o;
#pragma unroll
    for (int i = 0; i < 8; ++i) {
        float v = fmaxf(fmaf(acc[i], dn, bias[lane * 8 + i]), 0.f);
        o[i] = (_Float16)v;
        red[grp][lane * 8 + i] = v;
    }
    __builtin_nontemporal_store(o, &A8[(size_t)node * 16 + lane]);
    __syncthreads();
    if (threadIdx.x < 128) {
        int c = threadIdx.x;
        float s = 0.f, s2 = 0.f;
#pragma unroll
        for (int g = 0; g < 16; ++g) {
            float v = red[g][c];
            s += v;
            s2 = fmaf(v, v, s2);
        }
        float* p = part + (size_t)(blockIdx.x & 31) * 256;
        atomicAdd(&p[c], s);
        atomicAdd(&p[128 + c], s2);
    }
}

// ---------------- pooling (+ fused layer-3 BN coeffs) ----------------
__global__ __launch_bounds__(256) void k_pool(const h8* __restrict__ x8,
                                              const int* __restrict__ starts,
                                              const float* __restrict__ part,
                                              const float* __restrict__ g,
                                              const float* __restrict__ beta,
                                              float* __restrict__ pooled) {
    __shared__ float a_s[128], c_s[128];
    int t = threadIdx.x;
    if (t < 128) {
        float s = 0.f, s2 = 0.f;
        for (int st = 0; st < 32; ++st) {
            s += part[st * 256 + t];
            s2 += part[st * 256 + 128 + t];
        }
        float m = s * (1.0f / N_NODES);
        float v = s2 * (1.0f / N_NODES) - m * m;
        float ai = g[t] * rsqrtf(v + EPS);
        a_s[t] = ai;
        c_s[t] = beta[t] - m * ai;
    }
    __syncthreads();
    int gg = blockIdx.x;
    int grp = t >> 4;
    int lane = t & 15;
    int beg = starts[gg], end = starts[gg + 1];
    float s[8] = {};
    for (int n = beg + grp; n < end; n += 16) {
        h8 v = x8[(size_t)n * 16 + lane];
#pragma unroll
        for (int i = 0; i < 8; ++i) s[i] += (float)v[i];
    }
    __shared__ float red[16][128];
#pragma unroll
    for (int i = 0; i < 8; ++i) red[grp][lane * 8 + i] = s[i];
    __syncthreads();
    if (t < 128) {
        int ch = t;
        float tt = 0.f;
#pragma unroll
        for (int gi = 0; gi < 16; ++gi) tt += red[gi][ch];
        float cnt = (float)(end - beg);
        pooled[gg * D + ch] = fmaf(a_s[ch], tt, cnt * c_s[ch]);
    }
}

// dense + relu + fused stats atomics; BN coeffs computed in-block from stats_in
template <int K, bool BN>
__global__ __launch_bounds__(256) void k_dense(const float* __restrict__ in,
                                               const float* __restrict__ W,
                                               const float* __restrict__ b,
                                               const float* __restrict__ stats_in,
                                               const float* __restrict__ g,
                                               const float* __restrict__ beta,
                                               float* __restrict__ out,
                                               float* __restrict__ stats_out) {
    __shared__ float inl[K];
    __shared__ float a_s[K > 128 ? K : 1], c_s[K > 128 ? K : 1];
    int t = threadIdx.x;
    if (BN) {
        float s = 0.f, s2 = 0.f;
        for (int st = 0; st < 8; ++st) {
            s += stats_in[st * 512 + t];
            s2 += stats_in[st * 512 + 256 + t];
        }
        float m = s * (1.0f / N_GRAPHS);
        float v = s2 * (1.0f / N_GRAPHS) - m * m;
        float ai = g[t] * rsqrtf(v + EPS);
        a_s[t] = ai;
        c_s[t] = beta[t] - m * ai;
        __syncthreads();
    }
    int row = blockIdx.x;
    for (int k = t; k < K; k += 256) {
        float v = in[row * K + k];
        if (BN) v = fmaf(v, a_s[k], c_s[k]);
        inl[k] = v;
    }
    __syncthreads();
    int j = t;
    float acc = b[j];
#pragma unroll
    for (int k = 0; k < K; ++k) acc = fmaf(inl[k], W[k * 256 + j], acc);
    float v = fmaxf(acc, 0.0f);
    out[row * 256 + j] = v;
    float* sp = stats_out + (size_t)(row & 7) * 512;
    atomicAdd(&sp[j], v);
    atomicAdd(&sp[256 + j], v * v);
}

// final dot with h1's BN computed in-block and applied in-register
__global__ __launch_bounds__(256) void k_final(const float* __restrict__ h,
                                               const float* __restrict__ stats_in,
                                               const float* __restrict__ gg,
                                               const float* __restrict__ beta,
                                               const float* __restrict__ Wout,
                                               const float* __restrict__ bout,
                                               float* __restrict__ out) {
    __shared__ float a_s[256], c_s[256];
    int t = threadIdx.x;
    {
        float s = 0.f, s2 = 0.f;
        for (int st = 0; st < 8; ++st) {
            s += stats_in[st * 512 + t];
            s2 += stats_in[st * 512 + 256 + t];
        }
        float m = s * (1.0f / N_GRAPHS);
        float v = s2 * (1.0f / N_GRAPHS) - m * m;
        float ai = gg[t] * rsqrtf(v + EPS);
        a_s[t] = ai;
        c_s[t] = beta[t] - m * ai;
    }
    __syncthreads();
    int g = blockIdx.x * 4 + (t >> 6);
    int lane = t & 63;
    float4 v = ((const float4*)(h + g * DH))[lane];
    float4 av = ((const float4*)a_s)[lane];
    float4 cv = ((const float4*)c_s)[lane];
    float4 w = ((const float4*)Wout)[lane];
    v.x = fmaf(v.x, av.x, cv.x);
    v.y = fmaf(v.y, av.y, cv.y);
    v.z = fmaf(v.z, av.z, cv.z);
    v.w = fmaf(v.w, av.w, cv.w);
    float acc = v.x * w.x + v.y * w.y + v.z * w.z + v.w * w.w;
#pragma unroll
    for (int off = 32; off; off >>= 1) acc += __shfl_down(acc, off, 64);
    if (lane == 0) out[g] = acc + bout[0];
}

// ---------------- launch ----------------

extern "C" void kernel_launch(void* const* d_in, const int* in_sizes, int n_in,
                              void* d_out, int out_size, void* d_ws, size_t ws_size,
                              hipStream_t stream) {
    const float* x = (const float*)d_in[0];
    const int* ei = (const int*)d_in[1];
    const int* batch = (const int*)d_in[2];
    const float* Wc = (const float*)d_in[3];
    const float* bc = (const float*)d_in[4];
    const float* gc = (const float*)d_in[5];
    const float* bec = (const float*)d_in[6];
    const float* Wh0 = (const float*)d_in[7];
    const float* bh0 = (const float*)d_in[8];
    const float* gh0 = (const float*)d_in[9];
    const float* beh0 = (const float*)d_in[10];
    const float* Wh1 = (const float*)d_in[11];
    const float* bh1 = (const float*)d_in[12];
    const float* gh1 = (const float*)d_in[13];
    const float* beh1 = (const float*)d_in[14];
    const float* Wout = (const float*)d_in[15];
    const float* bout = (const float*)d_in[16];
    float* out = (float*)d_out;

    const int* src = ei;
    const int* dst = ei + N_EDGES;

    char* base = (char*)d_ws;
    size_t woff = 0;
    auto alloc = [&](size_t bytes) -> char* {
        char* p = base + woff;
        woff = (woff + bytes + 255) & ~(size_t)255;
        return p;
    };
    _Float16* bufY = (_Float16*)alloc(sizeof(_Float16) * (size_t)N_NODES * D);
    _Float16* bufA = (_Float16*)alloc(sizeof(_Float16) * (size_t)N_NODES * D);
    float* dinv = (float*)alloc(sizeof(float) * N_NODES);
    int* csr = (int*)alloc(sizeof(int) * N_EDGES);
    int* perm = (int*)alloc(sizeof(int) * N_NODES);
    unsigned* staging = (unsigned*)alloc(sizeof(unsigned) * 8 * PCAP);
    unsigned* stag2 = (unsigned*)alloc(sizeof(unsigned) * 512 * SBCAP);
    // zeroed: pcur(64) + pcur2(512) + part[3](3*32*256) + stats[2](2*8*512)
    size_t zero_bytes = sizeof(int) * (64 + 512) + sizeof(float) * (3 * 32 * 256 + 2 * 8 * 512);
    char* zero_base = alloc(zero_bytes);
    int* pcur = (int*)zero_base;
    int* pcur2 = pcur + 64;
    float* part = (float*)(pcur2 + 512);   // 3 layer-indexed buffers
    float* stats0 = part + 3 * 32 * 256;   // h0: 8 stripes x (256 sums + 256 sq)
    float* stats1 = stats0 + 8 * 512;      // h1
    int* offs = (int*)alloc(sizeof(int) * (N_NODES + 1));
    int* starts = (int*)alloc(sizeof(int) * (N_GRAPHS + 1));
    float* pooled = (float*)alloc(sizeof(float) * N_GRAPHS * D);
    float* h0 = (float*)alloc(sizeof(float) * N_GRAPHS * DH);
    float* h1 = (float*)alloc(sizeof(float) * N_GRAPHS * DH);

    hipMemsetAsync(zero_base, 0, zero_bytes, stream);

    int split_grid = (N_EDGES + FCHUNK - 1) / FCHUNK;
    int split2_grid = ((PCAP + CH2 - 1) / CH2) * 8;
    k_split<<<split_grid, 256, 0, stream>>>(src, dst, pcur, staging);
    k_split2<<<split2_grid, 256, 0, stream>>>(staging, pcur, pcur2, stag2);
    k_sort3<<<512, 256, 0, stream>>>(stag2, pcur2, batch, offs, dinv, csr, starts,
                                     perm);

    int gemm_grid = (N_NODES + 63) / 64;
    int agg_grid = N_NODES / 16;
    // layer 0: no BN fold (W used as-is), input fp32 x
    k_gemmf<true, false><<<gemm_grid, 256, 0, stream>>>(
        x, Wc + 0 * D * D, nullptr, nullptr, nullptr, dinv, bufY, N_NODES);
    k_aggregate<<<agg_grid, 256, 0, stream>>>((const h8*)bufY, offs, csr, dinv,
                                              bc + 0 * D, perm, (h8*)bufA, part);
    // layer 1: BN fold from part0
    k_gemmf<false, true><<<gemm_grid, 256, 0, stream>>>(
        bufA, Wc + 1 * D * D, part, gc + 0 * D, bec + 0 * D, dinv, bufY, N_NODES);
    k_aggregate<<<agg_grid, 256, 0, stream>>>((const h8*)bufY, offs, csr, dinv,
                                              bc + 1 * D, perm, (h8*)bufA,
                                              part + 1 * 32 * 256);
    // layer 2: BN fold from part1
    k_gemmf<false, true><<<gemm_grid, 256, 0, stream>>>(
        bufA, Wc + 2 * D * D, part + 1 * 32 * 256, gc + 1 * D, bec + 1 * D, dinv,
        bufY, N_NODES);
    k_aggregate<<<agg_grid, 256, 0, stream>>>((const h8*)bufY, offs, csr, dinv,
                                              bc + 2 * D, perm, (h8*)bufA,
                                              part + 2 * 32 * 256);

    // pool with fused layer-3 BN coeffs
    k_pool<<<N_GRAPHS, 256, 0, stream>>>((const h8*)bufA, starts,
                                         part + 2 * 32 * 256, gc + 2 * D,
                                         bec + 2 * D, pooled);

    k_dense<128, false><<<N_GRAPHS, 256, 0, stream>>>(pooled, Wh0, bh0, nullptr,
                                                      nullptr, nullptr, h0, stats0);
    k_dense<256, true><<<N_GRAPHS, 256, 0, stream>>>(h0, Wh1, bh1, stats0, gh0,
                                                     beh0, h1, stats1);
    k_final<<<N_GRAPHS / 4, 256, 0, stream>>>(h1, stats1, gh1, beh1, Wout, bout,
                                              out);
}